// Round 15
// baseline (53.520 us; speedup 1.0000x reference)
//
#include <hip/hip_runtime.h>
#include <hip/hip_bf16.h>

// Problem constants (KANLayer): B=8192, I=256, O=256, NUM_BASIS=7, ORDER=3
#define B_SZ 8192
#define I_SZ 256
#define O_SZ 256
#define KDIM 2048  // I_SZ * 8  (7 basis + 1 silu per input feature)
#define NPART 128  // min/max partial rows

typedef __bf16 bf16x8 __attribute__((ext_vector_type(8)));
typedef float f32x4 __attribute__((ext_vector_type(4)));

// Kernel 1: per-column min/max partials (proven r7 shape).
__global__ __launch_bounds__(256) void minmax_partial(
    const float* __restrict__ x, float* __restrict__ pmin,
    float* __restrict__ pmax) {
  const int cg = threadIdx.x & 63;
  const int rs = threadIdx.x >> 6;
  const int r0 = blockIdx.x * 64;
  const float* p = x + (size_t)(r0 + rs) * I_SZ + cg * 4;
  float4 mn = {1e30f, 1e30f, 1e30f, 1e30f};
  float4 mx = {-1e30f, -1e30f, -1e30f, -1e30f};
#pragma unroll
  for (int k = 0; k < 16; ++k) {
    const float4 v = *reinterpret_cast<const float4*>(p + (size_t)k * 4 * I_SZ);
    mn.x = fminf(mn.x, v.x); mn.y = fminf(mn.y, v.y);
    mn.z = fminf(mn.z, v.z); mn.w = fminf(mn.w, v.w);
    mx.x = fmaxf(mx.x, v.x); mx.y = fmaxf(mx.y, v.y);
    mx.z = fmaxf(mx.z, v.z); mx.w = fmaxf(mx.w, v.w);
  }
  __shared__ float rmn[4][I_SZ], rmx[4][I_SZ];
  *reinterpret_cast<float4*>(&rmn[rs][cg * 4]) = mn;
  *reinterpret_cast<float4*>(&rmx[rs][cg * 4]) = mx;
  __syncthreads();
  if (threadIdx.x < 64) {
    float4 a, b;
    const int c0 = threadIdx.x * 4;
    a.x = fminf(fminf(rmn[0][c0+0], rmn[1][c0+0]), fminf(rmn[2][c0+0], rmn[3][c0+0]));
    a.y = fminf(fminf(rmn[0][c0+1], rmn[1][c0+1]), fminf(rmn[2][c0+1], rmn[3][c0+1]));
    a.z = fminf(fminf(rmn[0][c0+2], rmn[1][c0+2]), fminf(rmn[2][c0+2], rmn[3][c0+2]));
    a.w = fminf(fminf(rmn[0][c0+3], rmn[1][c0+3]), fminf(rmn[2][c0+3], rmn[3][c0+3]));
    b.x = fmaxf(fmaxf(rmx[0][c0+0], rmx[1][c0+0]), fmaxf(rmx[2][c0+0], rmx[3][c0+0]));
    b.y = fmaxf(fmaxf(rmx[0][c0+1], rmx[1][c0+1]), fmaxf(rmx[2][c0+1], rmx[3][c0+1]));
    b.z = fmaxf(fmaxf(rmx[0][c0+2], rmx[1][c0+2]), fmaxf(rmx[2][c0+2], rmx[3][c0+2]));
    b.w = fmaxf(fmaxf(rmx[0][c0+3], rmx[1][c0+3]), fmaxf(rmx[2][c0+3], rmx[3][c0+3]));
    *reinterpret_cast<float4*>(&pmin[blockIdx.x * I_SZ + c0]) = a;
    *reinterpret_cast<float4*>(&pmax[blockIdx.x * I_SZ + c0]) = b;
  }
}

// Kernel 2: pack weights -> Wp[o, i*8+m] bf16, pre-swizzled (unit ^= o&7),
// PLUS (block 0) reduce min/max partials into (rhw, -centre*rhw).
__global__ void pack_W(const float* __restrict__ bw,
                       const float* __restrict__ sw,
                       const float* __restrict__ coeff,
                       __hip_bfloat16* __restrict__ W,
                       const float* __restrict__ pmin,
                       const float* __restrict__ pmax,
                       float* __restrict__ cenrhw) {
  const int idx = blockIdx.x * blockDim.x + threadIdx.x;
  const int i = idx & (I_SZ - 1);
  const int o = idx >> 8;
  const float s = sw[idx];
  union { __hip_bfloat16 h[8]; float4 f4; } u;
#pragma unroll
  for (int m = 0; m < 7; ++m)
    u.h[m] = __float2bfloat16(coeff[(size_t)idx * 7 + m] * s);
  u.h[7] = __float2bfloat16(bw[idx]);
  const size_t off = (size_t)o * KDIM + (size_t)((i ^ (o & 7)) << 3);
  *reinterpret_cast<float4*>(&W[off]) = u.f4;

  if (blockIdx.x == 0) {
    const int c = threadIdx.x;
    float mn = 1e30f, mx = -1e30f;
#pragma unroll 8
    for (int p = 0; p < NPART; ++p) {
      mn = fminf(mn, pmin[p * I_SZ + c]);
      mx = fmaxf(mx, pmax[p * I_SZ + c]);
    }
    const float width = fmaxf(mx - mn, 0.01f);
    const float rhw = 2.0f / width;
    cenrhw[2 * c]     = rhw;
    cenrhw[2 * c + 1] = -0.5f * (mx + mn) * rhw;
  }
}

// Kernel 3: build A (R=1: ONE eval per element, the whole point).
// A[b, i*8+m] bf16, pre-swizzled (unit ^= b&7) to match gemm's linear
// global_load_lds + XOR'd ds_read. Coalesced: thread idx -> consecutive i,
// 16B stores permuted within 128B segments only. HBM-bound (~40MB).
__global__ __launch_bounds__(256) void build_A(
    const float* __restrict__ x, const float* __restrict__ cenrhw,
    __hip_bfloat16* __restrict__ A) {
  const int idx = blockIdx.x * blockDim.x + threadIdx.x;  // 0..B*I-1
  const int i = idx & (I_SZ - 1);
  const int b = idx >> 8;
  const float2 s2 = reinterpret_cast<const float2*>(cenrhw)[i];
  // closed-form uniform cubic B-spline (== reference's truncated de Boor):
  // xn in [-1,1] by construction; cell c = floor((xn+1)*5) capped at 6,
  // u = frac; slots c-3..c get q0..q3 (x 1/6); zero for sp>7.
  const float xn = __builtin_fmaf(x[idx], s2.x, s2.y);
  const float sp = __builtin_fmaf(xn, 5.0f, 5.0f);
  const float c6 = fminf(fmaxf(floorf(sp), 0.0f), 6.0f);
  const int ci = (int)c6;
  const float u = sp - c6;
  const float zm = (sp > 7.0f) ? 0.0f : (1.0f / 6.0f);
  const float u2 = u * u, u3 = u2 * u, t1 = 1.0f - u;
  const float q3 = u3 * zm;
  const float q0 = (t1 * t1) * (t1 * zm);
  float h2 = __builtin_fmaf(-3.0f, u, 3.0f);
  h2 = __builtin_fmaf(h2, u, 3.0f);
  h2 = __builtin_fmaf(h2, u, 1.0f);                 // -3u^3+3u^2+3u+1
  const float q2 = h2 * zm;
  float h1 = __builtin_fmaf(3.0f, u, -6.0f);
  h1 = __builtin_fmaf(h1, u2, 4.0f);                // 3u^3-6u^2+4
  const float q1 = h1 * zm;
  const float silu = xn * __builtin_amdgcn_rcpf(1.0f + __expf(-xn));
  union { __hip_bfloat16 h[8]; float4 f4; } uu;
#pragma unroll
  for (int j = 0; j < 7; ++j) {
    float v = 0.0f;
    v = (ci == j + 3) ? q0 : v;
    v = (ci == j + 2) ? q1 : v;
    v = (ci == j + 1) ? q2 : v;
    v = (ci == j)     ? q3 : v;
    uu.h[j] = __float2bfloat16(v);
  }
  uu.h[7] = __float2bfloat16(silu);
  const size_t off = (size_t)b * KDIM + (size_t)((i ^ (b & 7)) << 3);
  *reinterpret_cast<float4*>(&A[off]) = uu.f4;
}

// ---- async global->LDS 16B copy ----
__device__ __forceinline__ void async16(const __hip_bfloat16* g, __hip_bfloat16* l) {
  __builtin_amdgcn_global_load_lds(
      (const __attribute__((address_space(1))) void*)g,
      (__attribute__((address_space(3))) void*)l, 16, 0, 0);
}

// Kernel 4: classic GEMM out = A @ W^T + bias (r1-proven structure, ~21us).
// BM=BN=BK=64, 256 threads (4 waves, 2x2), 2-phase double-buffered LDS,
// global_load_lds width-16 staging, XOR-swizzled LDS reads (source-side swz).
// Grid 512 = 2 blocks/CU; bn-minor XCD swizzle -> 4 bn-blocks share A panel
// in their XCD's L2.
__global__ __launch_bounds__(256, 2) void gemm_kan(
    const __hip_bfloat16* __restrict__ A, const __hip_bfloat16* __restrict__ W,
    const float* __restrict__ bias, float* __restrict__ out) {
  __shared__ __align__(16) __hip_bfloat16 Alds[2][64 * 64];
  __shared__ __align__(16) __hip_bfloat16 Blds[2][64 * 64];

  const int t = threadIdx.x;
  const int lane = t & 63;
  const int wave = t >> 6;
  const int wm = wave >> 1, wn = wave & 1;   // wave grid 2x2 over 64x64 tile
  const int fr = lane & 15, fk = lane >> 4;

  const int bid = blockIdx.x;
  const int swz = (bid & 7) * ((int)gridDim.x >> 3) + (bid >> 3);
  const int bm = swz >> 2, bn = swz & 3;  // N/BN = 4, bn-minor
  const int rowBase = bm * 64, colBase = bn * 64;

  const int srow = t >> 3, sseg = t & 7;
  const __hip_bfloat16* ga = A + (size_t)(rowBase + srow) * KDIM + sseg * 8;
  const __hip_bfloat16* gb = W + (size_t)(colBase + srow) * KDIM + sseg * 8;

  f32x4 acc[2][2] = {{{0.f, 0.f, 0.f, 0.f}, {0.f, 0.f, 0.f, 0.f}},
                     {{0.f, 0.f, 0.f, 0.f}, {0.f, 0.f, 0.f, 0.f}}};

  auto stage = [&](int buf, int kt) {
    const size_t k0 = (size_t)kt * 64;
    async16(ga + k0, &Alds[buf][t * 8]);
    async16(ga + k0 + (size_t)32 * KDIM, &Alds[buf][2048 + t * 8]);
    async16(gb + k0, &Blds[buf][t * 8]);
    async16(gb + k0 + (size_t)32 * KDIM, &Blds[buf][2048 + t * 8]);
  };

  auto compute = [&](int buf) {
    bf16x8 af[2][2], bg[2][2];
#pragma unroll
    for (int m = 0; m < 2; ++m)
#pragma unroll
      for (int kk = 0; kk < 2; ++kk) {
        const int row = wm * 32 + m * 16 + fr;
        const int eo = row * 64 + ((((kk << 2) | fk) ^ (row & 7)) << 3);
        af[m][kk] = *reinterpret_cast<const bf16x8*>(&Alds[buf][eo]);
      }
#pragma unroll
    for (int n = 0; n < 2; ++n)
#pragma unroll
      for (int kk = 0; kk < 2; ++kk) {
        const int row = wn * 32 + n * 16 + fr;
        const int eo = row * 64 + ((((kk << 2) | fk) ^ (row & 7)) << 3);
        bg[n][kk] = *reinterpret_cast<const bf16x8*>(&Blds[buf][eo]);
      }
#pragma unroll
    for (int kk = 0; kk < 2; ++kk)
#pragma unroll
      for (int m = 0; m < 2; ++m)
#pragma unroll
        for (int n = 0; n < 2; ++n)
          acc[m][n] = __builtin_amdgcn_mfma_f32_16x16x32_bf16(
              af[m][kk], bg[n][kk], acc[m][n], 0, 0, 0);
  };

  stage(0, 0);
  __syncthreads();
  int cur = 0;
  const int NT = KDIM / 64;  // 32
  for (int kt = 0; kt < NT - 1; ++kt) {
    stage(cur ^ 1, kt + 1);
    compute(cur);
    __syncthreads();
    cur ^= 1;
  }
  compute(cur);

  // epilogue: C/D layout col=lane&15, row=(lane>>4)*4+reg  [m89/m91]
#pragma unroll
  for (int m = 0; m < 2; ++m)
#pragma unroll
    for (int n = 0; n < 2; ++n) {
      const int col = colBase + wn * 32 + n * 16 + fr;
      const float bc = bias[col];
#pragma unroll
      for (int r = 0; r < 4; ++r) {
        const int row = rowBase + wm * 32 + m * 16 + fk * 4 + r;
        out[(size_t)row * O_SZ + col] = acc[m][n][r] + bc;
      }
    }
}

extern "C" void kernel_launch(void* const* d_in, const int* in_sizes, int n_in,
                              void* d_out, int out_size, void* d_ws, size_t ws_size,
                              hipStream_t stream) {
  const float* x     = (const float*)d_in[0];
  const float* bw    = (const float*)d_in[1];
  const float* sw    = (const float*)d_in[2];
  const float* coeff = (const float*)d_in[3];
  const float* bias  = (const float*)d_in[4];
  float* out = (float*)d_out;

  char* ws = (char*)d_ws;
  __hip_bfloat16* Abuf = (__hip_bfloat16*)ws;                               // 32 MiB
  __hip_bfloat16* Wbuf = (__hip_bfloat16*)(ws + (size_t)B_SZ * KDIM * 2);   // 1 MiB
  float* pmin   = (float*)(ws + (size_t)B_SZ * KDIM * 2 + (size_t)O_SZ * KDIM * 2);
  float* pmax   = pmin + NPART * I_SZ;
  float* cenrhw = pmax + NPART * I_SZ;

  minmax_partial<<<NPART, 256, 0, stream>>>(x, pmin, pmax);
  pack_W<<<(O_SZ * I_SZ) / 256, 256, 0, stream>>>(bw, sw, coeff, Wbuf,
                                                  pmin, pmax, cenrhw);
  build_A<<<(B_SZ * I_SZ) / 256, 256, 0, stream>>>(x, cenrhw, Abuf);
  gemm_kan<<<(B_SZ / 64) * (O_SZ / 64), 256, 0, stream>>>(Abuf, Wbuf, bias, out);
}